// Round 7
// baseline (368.634 us; speedup 1.0000x reference)
//
#include <hip/hip_runtime.h>
#include <hip/hip_bf16.h>
#include <stdint.h>

#define T_TOK 1024
#define HDIM  1024
#define NEXP  16
#define IDIM  2880
#define GU_COLS (2*IDIM)   // 5760
#define TOPK  4

using short8   = __attribute__((ext_vector_type(8))) short;
using ushort4v = __attribute__((ext_vector_type(4))) unsigned short;
using f32x4    = __attribute__((ext_vector_type(4))) float;

__device__ __forceinline__ unsigned short f2b(float f) {
    union { float f; unsigned u; } x; x.f = f;
    unsigned r = x.u + 0x7FFFu + ((x.u >> 16) & 1u);  // RNE
    return (unsigned short)(r >> 16);
}

typedef const __attribute__((address_space(1))) unsigned int* gas1_t;
typedef __attribute__((address_space(3))) unsigned int* las3_t;
__device__ __forceinline__ void gload16(const void* g, void* l) {
    __builtin_amdgcn_global_load_lds((gas1_t)g, (las3_t)l, 16, 0, 0);
}

// ---------------- Kernel 1: router + x->bf16 + zero out ---------------------
__global__ __launch_bounds__(256) void router_kernel(
    const float* __restrict__ x, const float* __restrict__ gw,
    const float* __restrict__ gb, float* __restrict__ logits_out,
    int* __restrict__ counts, int* __restrict__ lists, float* __restrict__ wts,
    unsigned short* __restrict__ xb, float* __restrict__ out)
{
    int t = blockIdx.x;
    int tid = threadIdx.x;
    const float* xr = x + (size_t)t * HDIM;
    {
        float4 v = *(const float4*)(xr + tid * 4);
        ushort4v b; b.x = f2b(v.x); b.y = f2b(v.y); b.z = f2b(v.z); b.w = f2b(v.w);
        *(ushort4v*)(xb + (size_t)t * HDIM + tid * 4) = b;
        float4 z = make_float4(0.f, 0.f, 0.f, 0.f);
        *(float4*)(out + (size_t)t * HDIM + tid * 4) = z;
    }
    int e = tid >> 4;
    int l16 = tid & 15;
    const float* wr = gw + (size_t)e * HDIM;
    float p = 0.f;
    for (int h = l16; h < HDIM; h += 16) p += xr[h] * wr[h];
    p += __shfl_xor(p, 8);
    p += __shfl_xor(p, 4);
    p += __shfl_xor(p, 2);
    p += __shfl_xor(p, 1);
    __shared__ float sl[NEXP];
    if (l16 == 0) {
        float v = p + gb[e];
        sl[e] = v;
        logits_out[t * NEXP + e] = v;
    }
    __syncthreads();
    if (tid == 0) {
        float v[NEXP];
#pragma unroll
        for (int i = 0; i < NEXP; ++i) v[i] = sl[i];
        int idx[TOPK]; float tv[TOPK];
        unsigned used = 0;
#pragma unroll
        for (int k = 0; k < TOPK; ++k) {
            float best = -__builtin_inff(); int bi = 0;
#pragma unroll
            for (int i = 0; i < NEXP; ++i)
                if (!((used >> i) & 1u) && v[i] > best) { best = v[i]; bi = i; }
            used |= 1u << bi; idx[k] = bi; tv[k] = best;
        }
        float m = tv[0];
        float ex[TOPK], s = 0.f;
#pragma unroll
        for (int k = 0; k < TOPK; ++k) { ex[k] = expf(tv[k] - m); s += ex[k]; }
#pragma unroll
        for (int k = 0; k < TOPK; ++k) {
            float w = ex[k] / s;
            int slot = atomicAdd(&counts[idx[k]], 1);
            lists[idx[k] * T_TOK + slot] = t;
            wts[idx[k] * T_TOK + slot] = w;
        }
    }
}

// ---------------- Kernel 2: exclusive prefix sum ---------------------------
__global__ void offsets_kernel(const int* __restrict__ counts, int* __restrict__ offsets)
{
    if (threadIdx.x == 0) {
        int o = 0;
        for (int e = 0; e < NEXP; ++e) { offsets[e] = o; o += counts[e]; }
        offsets[NEXP] = o;
    }
}

// ---------------- Kernel 3: gate_up GEMM + silu (direct fp32 weights) ------
// BM=256 tokens x 64 out cols as 128 B-rows interleaved
// [gate c0-31][up c0-31][gate c32-63][up c32-63]. BK=64, K=HDIM.
// 8 waves 4M x 2N, wave tile 64 rows x 64 B-rows. launch_bounds(512,4)
// pins VGPR<=128 -> 2 blocks/CU (cross-block stage/compute overlap).
// B swizzle: unit u ^= (n&7)<<1 (keeps bit0 -> single ds_read_b128 frags).
__global__ __launch_bounds__(512, 4) void gu_kernel(
    const unsigned short* __restrict__ xb, const float* __restrict__ gup,
    const float* __restrict__ gub, const int* __restrict__ counts,
    const int* __restrict__ offsets, const int* __restrict__ lists,
    unsigned short* __restrict__ inter)
{
    int bid = blockIdx.x;
    int nt = bid % 45;
    int t2 = bid / 45;
    int e  = t2 & 15;
    int mt = t2 >> 4;          // HIGH bits: 0..3
    int ne = counts[e];
    if (mt * 256 >= ne) return;

    int tid = threadIdx.x;
    int wave = tid >> 6, lane = tid & 63;
    int l16 = lane & 15, lq = lane >> 4;
    int wm = wave >> 1, wn = wave & 1;

    __shared__ int tokid[256];
    __shared__ unsigned short As[256 * 64];   // 32 KB
    __shared__ unsigned short Bs[128 * 64];   // 16 KB

    if (tid < 256) {
        int slot = mt * 256 + tid;
        tokid[tid] = (slot < ne) ? lists[e * T_TOK + slot] : lists[e * T_TOK];
    }
    __syncthreads();

    const float* gup_e = gup + (size_t)e * HDIM * GU_COLS;

    // A: all 512 threads, 4 x 16B chunks each (2048 chunks)
    const unsigned short* asrc[4];
#pragma unroll
    for (int i = 0; i < 4; ++i) {
        int s = tid + i * 512;
        int row = s >> 3, c = s & 7;
        asrc[i] = xb + (size_t)tokid[row] * HDIM + ((c ^ (row & 7)) * 8);
    }
    // B: thread -> (nb 0..15, kb 0..15, h 0..1); col-group g = nb + h*16
    int nb = tid & 15, kb = (tid >> 4) & 15, bh = tid >> 8;
    int g = nb + bh * 16;
    int n0 = g * 4;
    int is_up = (n0 >> 5) & 1;
    int cwb = (n0 & 31) + ((n0 >> 6) << 5);
    const float* bsrc = gup_e + (size_t)(kb * 4) * GU_COLS
                      + (is_up ? (size_t)IDIM : 0) + (size_t)nt * 64 + cwb;

    f32x4 acc[4][4];
#pragma unroll
    for (int i = 0; i < 4; ++i)
#pragma unroll
        for (int f = 0; f < 4; ++f) acc[i][f] = (f32x4){0.f, 0.f, 0.f, 0.f};

    for (int kk = 0; kk < HDIM; kk += 64) {
        __syncthreads();                       // prev readers done
        // A stage (async LDS-DMA, stays in flight during B load/convert)
#pragma unroll
        for (int i = 0; i < 4; ++i)
            gload16(asrc[i] + kk, As + ((size_t)(tid + i * 512)) * 8);
        // B stage: 4 k-rows x 4 cols fp32 -> bf16 transposed + swizzled
        {
            const float* sp = bsrc + (size_t)kk * GU_COLS;
            float4 r0 = *(const float4*)(sp);
            float4 r1 = *(const float4*)(sp + GU_COLS);
            float4 r2 = *(const float4*)(sp + 2 * GU_COLS);
            float4 r3 = *(const float4*)(sp + 3 * GU_COLS);
#pragma unroll
            for (int j = 0; j < 4; ++j) {
                int n = n0 + j;
                int slot = kb ^ ((n & 7) << 1);
                ushort4v b;
                b.x = f2b((&r0.x)[j]); b.y = f2b((&r1.x)[j]);
                b.z = f2b((&r2.x)[j]); b.w = f2b((&r3.x)[j]);
                *(ushort4v*)&Bs[n * 64 + slot * 4] = b;
            }
        }
        __syncthreads();                       // drains A DMA + B writes
        __builtin_amdgcn_s_setprio(1);
#pragma unroll
        for (int ks = 0; ks < 2; ++ks) {
            short8 a[4], b[4];
#pragma unroll
            for (int i = 0; i < 4; ++i) {
                int row = wm * 64 + i * 16 + l16;
                int q = ks * 4 + lq;
                a[i] = *(const short8*)&As[row * 64 + ((q ^ (row & 7)) * 8)];
            }
#pragma unroll
            for (int f = 0; f < 4; ++f) {
                int n = wn * 64 + f * 16 + l16;
                int u = (ks * 8 + lq * 2) ^ ((n & 7) << 1);
                b[f] = *(const short8*)&Bs[n * 64 + u * 4];
            }
#pragma unroll
            for (int i = 0; i < 4; ++i)
#pragma unroll
                for (int f = 0; f < 4; ++f)
                    acc[i][f] = __builtin_amdgcn_mfma_f32_16x16x32_bf16(a[i], b[f], acc[i][f], 0, 0, 0);
        }
        __builtin_amdgcn_s_setprio(0);
    }

    // ---- epilogue: intra-wave silu(gate)*up ----
    int off = offsets[e];
    const float* gbe = gub + (size_t)e * GU_COLS;
#pragma unroll
    for (int j = 0; j < 2; ++j) {
        int cw = wn * 32 + j * 16 + l16;       // 0..63 within nt's 64 cols
        float bg = gbe[nt * 64 + cw];
        float bu = gbe[IDIM + nt * 64 + cw];
#pragma unroll
        for (int i = 0; i < 4; ++i)
#pragma unroll
            for (int r = 0; r < 4; ++r) {
                int row = wm * 64 + i * 16 + lq * 4 + r;
                int slot = mt * 256 + row;
                if (slot < ne) {
                    float gv = acc[i][j][r] + bg;
                    float uv = acc[i][j + 2][r] + bu;
                    float sg = gv / (1.f + expf(-gv));
                    inter[(size_t)(off + slot) * IDIM + nt * 64 + cw] = f2b(sg * uv);
                }
            }
    }
}

// ---------------- Kernel 4: down GEMM + weighted scatter (direct fp32) -----
// BM=256 slots x BN=128 h-cols, BK=64, K-split x4 (768/768/768/576).
// 8 waves 4M x 2N, wave 64x64. Partial sums atomicAdd; bias via ksp==0.
__global__ __launch_bounds__(512, 4) void down_kernel(
    const unsigned short* __restrict__ inter, const float* __restrict__ dw,
    const float* __restrict__ db, const int* __restrict__ counts,
    const int* __restrict__ offsets, const int* __restrict__ lists,
    const float* __restrict__ wts, float* __restrict__ out)
{
    int bid = blockIdx.x;
    int ht  = bid & 7;
    int e   = (bid >> 3) & 15;
    int ksp = (bid >> 7) & 3;
    int mt  = bid >> 9;        // HIGH bits: 0..3
    int ne = counts[e];
    if (mt * 256 >= ne) return;

    int k0   = ksp * 768;
    int kend = (k0 + 768 < IDIM) ? (k0 + 768) : IDIM;

    int tid = threadIdx.x;
    int wave = tid >> 6, lane = tid & 63;
    int l16 = lane & 15, lq = lane >> 4;
    int wm = wave >> 1, wn = wave & 1;

    __shared__ int tokid[256];
    __shared__ float twt[256];
    __shared__ unsigned short As[256 * 64];   // 32 KB
    __shared__ unsigned short Bs[128 * 64];   // 16 KB

    int off = offsets[e];
    if (tid < 256) {
        int slot = mt * 256 + tid;
        tokid[tid] = (slot < ne) ? lists[e * T_TOK + slot] : -1;
        twt[tid]   = (slot < ne) ? wts[e * T_TOK + slot] : 0.f;
    }
    __syncthreads();

    const float* dw_e = dw + (size_t)e * IDIM * HDIM;

    const unsigned short* asrc[4];
#pragma unroll
    for (int i = 0; i < 4; ++i) {
        int s = tid + i * 512;
        int row = s >> 3, c = s & 7;
        int slotr = mt * 256 + row; if (slotr >= ne) slotr = ne - 1;
        asrc[i] = inter + (size_t)(off + slotr) * IDIM + ((c ^ (row & 7)) * 8);
    }
    int nb = tid & 15, kb = (tid >> 4) & 15, bh = tid >> 8;
    int g = nb + bh * 16;
    int n0 = g * 4;
    const float* bsrc = dw_e + (size_t)(kb * 4) * HDIM + ht * 128 + n0;

    f32x4 acc[4][4];
#pragma unroll
    for (int i = 0; i < 4; ++i)
#pragma unroll
        for (int f = 0; f < 4; ++f) acc[i][f] = (f32x4){0.f, 0.f, 0.f, 0.f};

    for (int kk = k0; kk < kend; kk += 64) {
        __syncthreads();
#pragma unroll
        for (int i = 0; i < 4; ++i)
            gload16(asrc[i] + kk, As + ((size_t)(tid + i * 512)) * 8);
        {
            const float* sp = bsrc + (size_t)kk * HDIM;
            float4 r0 = *(const float4*)(sp);
            float4 r1 = *(const float4*)(sp + HDIM);
            float4 r2 = *(const float4*)(sp + 2 * HDIM);
            float4 r3 = *(const float4*)(sp + 3 * HDIM);
#pragma unroll
            for (int j = 0; j < 4; ++j) {
                int n = n0 + j;
                int slot = kb ^ ((n & 7) << 1);
                ushort4v b;
                b.x = f2b((&r0.x)[j]); b.y = f2b((&r1.x)[j]);
                b.z = f2b((&r2.x)[j]); b.w = f2b((&r3.x)[j]);
                *(ushort4v*)&Bs[n * 64 + slot * 4] = b;
            }
        }
        __syncthreads();
        __builtin_amdgcn_s_setprio(1);
#pragma unroll
        for (int ks = 0; ks < 2; ++ks) {
            short8 a[4], b[4];
#pragma unroll
            for (int i = 0; i < 4; ++i) {
                int row = wm * 64 + i * 16 + l16;
                int q = ks * 4 + lq;
                a[i] = *(const short8*)&As[row * 64 + ((q ^ (row & 7)) * 8)];
            }
#pragma unroll
            for (int f = 0; f < 4; ++f) {
                int n = wn * 64 + f * 16 + l16;
                int u = (ks * 8 + lq * 2) ^ ((n & 7) << 1);
                b[f] = *(const short8*)&Bs[n * 64 + u * 4];
            }
#pragma unroll
            for (int i = 0; i < 4; ++i)
#pragma unroll
                for (int f = 0; f < 4; ++f)
                    acc[i][f] = __builtin_amdgcn_mfma_f32_16x16x32_bf16(a[i], b[f], acc[i][f], 0, 0, 0);
        }
        __builtin_amdgcn_s_setprio(0);
    }

    const float* db_e = db + (size_t)e * HDIM;
#pragma unroll
    for (int f = 0; f < 4; ++f) {
        int h = ht * 128 + wn * 64 + f * 16 + l16;
        float bias = (ksp == 0) ? db_e[h] : 0.f;
#pragma unroll
        for (int i = 0; i < 4; ++i)
#pragma unroll
            for (int r = 0; r < 4; ++r) {
                int row = wm * 64 + i * 16 + lq * 4 + r;
                int tk = tokid[row];
                if (tk >= 0)
                    atomicAdd(out + (size_t)tk * HDIM + h, twt[row] * (acc[i][f][r] + bias));
            }
    }
}

// ---------------------------------------------------------------------------
extern "C" void kernel_launch(void* const* d_in, const int* in_sizes, int n_in,
                              void* d_out, int out_size, void* d_ws, size_t ws_size,
                              hipStream_t stream)
{
    const float* x   = (const float*)d_in[0];
    const float* gw  = (const float*)d_in[1];
    const float* gb  = (const float*)d_in[2];
    const float* gup = (const float*)d_in[3];
    const float* gub = (const float*)d_in[4];
    const float* dw  = (const float*)d_in[5];
    const float* db  = (const float*)d_in[6];

    float* out        = (float*)d_out;
    float* logits_out = out + (size_t)T_TOK * HDIM;

    char* ws = (char*)d_ws;
    int*   counts  = (int*)(ws + 0);
    int*   offsets = (int*)(ws + 256);
    int*   lists   = (int*)(ws + 512);                       // 64 KB
    float* wts     = (float*)(ws + 512 + 65536);             // 64 KB
    unsigned short* xb    = (unsigned short*)(ws + 131584);  // 2 MB
    unsigned short* inter = (unsigned short*)(ws + 2228736); // 23.6 MB

    hipMemsetAsync(counts, 0, 64, stream);

    router_kernel<<<T_TOK, 256, 0, stream>>>(x, gw, gb, logits_out, counts, lists, wts, xb, out);
    offsets_kernel<<<1, 64, 0, stream>>>(counts, offsets);
    gu_kernel<<<4 * NEXP * 45, 512, 0, stream>>>(xb, gup, gub, counts, offsets, lists, inter);
    down_kernel<<<4 * 4 * NEXP * 8, 512, 0, stream>>>(inter, dw, db, counts, offsets, lists, wts, out);
}

// Round 8
// 334.413 us; speedup vs baseline: 1.1023x; 1.1023x over previous
//
#include <hip/hip_runtime.h>
#include <hip/hip_bf16.h>
#include <stdint.h>

#define T_TOK 1024
#define HDIM  1024
#define NEXP  16
#define IDIM  2880
#define GU_COLS (2*IDIM)   // 5760
#define TOPK  4

using short8   = __attribute__((ext_vector_type(8))) short;
using ushort4v = __attribute__((ext_vector_type(4))) unsigned short;
using f32x4    = __attribute__((ext_vector_type(4))) float;

__device__ __forceinline__ unsigned short f2b(float f) {
    union { float f; unsigned u; } x; x.f = f;
    unsigned r = x.u + 0x7FFFu + ((x.u >> 16) & 1u);  // RNE
    return (unsigned short)(r >> 16);
}

typedef const __attribute__((address_space(1))) unsigned int* gas1_t;
typedef __attribute__((address_space(3))) unsigned int* las3_t;
__device__ __forceinline__ void gload16(const void* g, void* l) {
    __builtin_amdgcn_global_load_lds((gas1_t)g, (las3_t)l, 16, 0, 0);
}

// ---------------- Kernel 1: router + x->bf16 + zero out ---------------------
__global__ __launch_bounds__(256) void router_kernel(
    const float* __restrict__ x, const float* __restrict__ gw,
    const float* __restrict__ gb, float* __restrict__ logits_out,
    int* __restrict__ counts, int* __restrict__ lists, float* __restrict__ wts,
    unsigned short* __restrict__ xb, float* __restrict__ out)
{
    int t = blockIdx.x;
    int tid = threadIdx.x;
    const float* xr = x + (size_t)t * HDIM;
    {
        float4 v = *(const float4*)(xr + tid * 4);
        ushort4v b; b.x = f2b(v.x); b.y = f2b(v.y); b.z = f2b(v.z); b.w = f2b(v.w);
        *(ushort4v*)(xb + (size_t)t * HDIM + tid * 4) = b;
        float4 z = make_float4(0.f, 0.f, 0.f, 0.f);
        *(float4*)(out + (size_t)t * HDIM + tid * 4) = z;
    }
    int e = tid >> 4;
    int l16 = tid & 15;
    const float* wr = gw + (size_t)e * HDIM;
    float p = 0.f;
    for (int h = l16; h < HDIM; h += 16) p += xr[h] * wr[h];
    p += __shfl_xor(p, 8);
    p += __shfl_xor(p, 4);
    p += __shfl_xor(p, 2);
    p += __shfl_xor(p, 1);
    __shared__ float sl[NEXP];
    if (l16 == 0) {
        float v = p + gb[e];
        sl[e] = v;
        logits_out[t * NEXP + e] = v;
    }
    __syncthreads();
    if (tid == 0) {
        float v[NEXP];
#pragma unroll
        for (int i = 0; i < NEXP; ++i) v[i] = sl[i];
        int idx[TOPK]; float tv[TOPK];
        unsigned used = 0;
#pragma unroll
        for (int k = 0; k < TOPK; ++k) {
            float best = -__builtin_inff(); int bi = 0;
#pragma unroll
            for (int i = 0; i < NEXP; ++i)
                if (!((used >> i) & 1u) && v[i] > best) { best = v[i]; bi = i; }
            used |= 1u << bi; idx[k] = bi; tv[k] = best;
        }
        float m = tv[0];
        float ex[TOPK], s = 0.f;
#pragma unroll
        for (int k = 0; k < TOPK; ++k) { ex[k] = expf(tv[k] - m); s += ex[k]; }
#pragma unroll
        for (int k = 0; k < TOPK; ++k) {
            float w = ex[k] / s;
            int slot = atomicAdd(&counts[idx[k]], 1);
            lists[idx[k] * T_TOK + slot] = t;
            wts[idx[k] * T_TOK + slot] = w;
        }
    }
}

// ---------------- Kernel 2: exclusive prefix sum ---------------------------
__global__ void offsets_kernel(const int* __restrict__ counts, int* __restrict__ offsets)
{
    if (threadIdx.x == 0) {
        int o = 0;
        for (int e = 0; e < NEXP; ++e) { offsets[e] = o; o += counts[e]; }
        offsets[NEXP] = o;
    }
}

// ---------------- Kernel 3: gate_up GEMM + silu (direct fp32 weights) ------
// ROUND-5 STRUCTURE (best measured): BM=256, B tile 64 mixed rows
// (32 gate + 32 up cols), BK=64. 8 waves, wave = 32 rows x 64 B-rows,
// acc[2][4]. T14: B reg-prefetch issued after compute-releasing barrier.
// CHANGE vs r5: B swizzle slot = kb ^ (n&14) -> single ds_read_b128 frags
// in correct k-order; writes stay conflict-free.
__global__ __launch_bounds__(512) void gu_kernel(
    const unsigned short* __restrict__ xb, const float* __restrict__ gup,
    const float* __restrict__ gub, const int* __restrict__ counts,
    const int* __restrict__ offsets, const int* __restrict__ lists,
    unsigned short* __restrict__ inter)
{
    int bid = blockIdx.x;
    int nt = bid % 90;
    int t2 = bid / 90;
    int e  = t2 & 15;
    int mt = t2 >> 4;          // HIGH bits: 0..3
    int ne = counts[e];
    if (mt * 256 >= ne) return;

    int tid = threadIdx.x;
    int wave = tid >> 6, lane = tid & 63;
    int l16 = lane & 15, lq = lane >> 4;

    __shared__ int tokid[256];
    __shared__ unsigned short As[256 * 64];   // 32 KB
    __shared__ unsigned short Bs[64 * 64];    // 8 KB

    if (tid < 256) {
        int slot = mt * 256 + tid;
        tokid[tid] = (slot < ne) ? lists[e * T_TOK + slot] : lists[e * T_TOK];
    }
    __syncthreads();

    const float* gup_e = gup + (size_t)e * HDIM * GU_COLS;

    // A stagers: threads 256..511, 8 x 16B chunks each
    int at = tid - 256;
    const unsigned short* asrc[8];
    if (tid >= 256) {
#pragma unroll
        for (int i = 0; i < 8; ++i) {
            int s = at + i * 256;
            int row = s >> 3, c = s & 7;
            asrc[i] = xb + (size_t)tokid[row] * HDIM + ((c ^ (row & 7)) * 8);
        }
    }
    // B stagers: threads 0..255: nb = n-block(4 cols), kb = k-chunk(4 rows)
    int nb = tid & 15, kb = tid >> 4;
    const float* bsrc = nullptr;
    if (tid < 256) {
        int n0 = nb * 4;
        size_t col = (n0 < 32) ? (size_t)(nt * 32 + n0) : (size_t)(IDIM + nt * 32 + (n0 - 32));
        bsrc = gup_e + (size_t)(kb * 4) * GU_COLS + col;
    }

    f32x4 acc[2][4];
#pragma unroll
    for (int i = 0; i < 2; ++i)
#pragma unroll
        for (int f = 0; f < 4; ++f) acc[i][f] = (f32x4){0.f, 0.f, 0.f, 0.f};

    // B prologue: tile 0 into regs
    float4 br0, br1, br2, br3;
    if (tid < 256) {
        br0 = *(const float4*)(bsrc);
        br1 = *(const float4*)(bsrc + GU_COLS);
        br2 = *(const float4*)(bsrc + 2 * GU_COLS);
        br3 = *(const float4*)(bsrc + 3 * GU_COLS);
    }

    for (int kk = 0; kk < HDIM; kk += 64) {
        __syncthreads();                       // LDS free (prev readers done)
        if (tid >= 256) {
#pragma unroll
            for (int i = 0; i < 8; ++i)
                gload16(asrc[i] + kk, As + ((size_t)(at + i * 256)) * 8);
        } else {
            // convert + write B tile kk from regs
#pragma unroll
            for (int j = 0; j < 4; ++j) {
                int n = nb * 4 + j;
                int slot = kb ^ (n & 14);
                ushort4v b;
                b.x = f2b((&br0.x)[j]); b.y = f2b((&br1.x)[j]);
                b.z = f2b((&br2.x)[j]); b.w = f2b((&br3.x)[j]);
                *(ushort4v*)&Bs[n * 64 + slot * 4] = b;
            }
        }
        __syncthreads();                       // drains vmcnt (A) + lgkm (B)
        // T14: issue B loads for tile kk+64 — in flight during MFMA below
        if (tid < 256 && kk + 64 < HDIM) {
            const float* sp = bsrc + (size_t)(kk + 64) * GU_COLS;
            br0 = *(const float4*)(sp);
            br1 = *(const float4*)(sp + GU_COLS);
            br2 = *(const float4*)(sp + 2 * GU_COLS);
            br3 = *(const float4*)(sp + 3 * GU_COLS);
        }
        __builtin_amdgcn_s_setprio(1);
#pragma unroll
        for (int ks = 0; ks < 2; ++ks) {
            short8 a[2], b[4];
#pragma unroll
            for (int i = 0; i < 2; ++i) {
                int row = wave * 32 + i * 16 + l16;
                int q = ks * 4 + lq;
                a[i] = *(const short8*)&As[row * 64 + ((q ^ (row & 7)) * 8)];
            }
#pragma unroll
            for (int f = 0; f < 4; ++f) {
                int n = f * 16 + l16;
                int u = (ks * 8 + lq * 2) ^ (n & 14);
                b[f] = *(const short8*)&Bs[n * 64 + u * 4];
            }
#pragma unroll
            for (int i = 0; i < 2; ++i)
#pragma unroll
                for (int f = 0; f < 4; ++f)
                    acc[i][f] = __builtin_amdgcn_mfma_f32_16x16x32_bf16(a[i], b[f], acc[i][f], 0, 0, 0);
        }
        __builtin_amdgcn_s_setprio(0);
    }

    // ---- epilogue: intra-wave silu(gate)*up ----
    int off = offsets[e];
    const float* gbe = gub + (size_t)e * GU_COLS;
#pragma unroll
    for (int j = 0; j < 2; ++j) {
        int col = j * 16 + l16;
        float bg = gbe[nt * 32 + col];
        float bu = gbe[IDIM + nt * 32 + col];
#pragma unroll
        for (int i = 0; i < 2; ++i)
#pragma unroll
            for (int r = 0; r < 4; ++r) {
                int row = wave * 32 + i * 16 + lq * 4 + r;
                int slot = mt * 256 + row;
                if (slot < ne) {
                    float g = acc[i][j][r] + bg;
                    float u = acc[i][j + 2][r] + bu;
                    float sg = g / (1.f + expf(-g));
                    inter[(size_t)(off + slot) * IDIM + nt * 32 + col] = f2b(sg * u);
                }
            }
    }
}

// ---------------- Kernel 4: down GEMM + weighted scatter (direct fp32) -----
// ROUND-5 STRUCTURE + K-split x2 (0..1472, 1472..2880): live blocks
// 256 -> 512 = 2/CU (cross-block stage/compute overlap). Bias via ksp==0.
__global__ __launch_bounds__(512) void down_kernel(
    const unsigned short* __restrict__ inter, const float* __restrict__ dw,
    const float* __restrict__ db, const int* __restrict__ counts,
    const int* __restrict__ offsets, const int* __restrict__ lists,
    const float* __restrict__ wts, float* __restrict__ out)
{
    int bid = blockIdx.x;
    int ht  = bid & 15;
    int e   = (bid >> 4) & 15;
    int ksp = (bid >> 8) & 1;
    int mt  = bid >> 9;        // HIGH bits: 0..3
    int ne = counts[e];
    if (mt * 256 >= ne) return;

    int k0   = ksp * 1472;                 // 23 / 22 iterations
    int kend = ksp ? IDIM : 1472;

    int tid = threadIdx.x;
    int wave = tid >> 6, lane = tid & 63;
    int l16 = lane & 15, lq = lane >> 4;

    __shared__ int tokid[256];
    __shared__ float twt[256];
    __shared__ unsigned short As[256 * 64];   // 32 KB
    __shared__ unsigned short Bs[64 * 64];    // 8 KB

    int off = offsets[e];
    if (tid < 256) {
        int slot = mt * 256 + tid;
        tokid[tid] = (slot < ne) ? lists[e * T_TOK + slot] : -1;
        twt[tid]   = (slot < ne) ? wts[e * T_TOK + slot] : 0.f;
    }
    __syncthreads();

    const float* dw_e = dw + (size_t)e * IDIM * HDIM;

    int at = tid - 256;
    const unsigned short* asrc[8];
    if (tid >= 256) {
#pragma unroll
        for (int i = 0; i < 8; ++i) {
            int s = at + i * 256;
            int row = s >> 3, c = s & 7;
            int slotr = mt * 256 + row; if (slotr >= ne) slotr = ne - 1;
            asrc[i] = inter + (size_t)(off + slotr) * IDIM + ((c ^ (row & 7)) * 8);
        }
    }
    int nb = tid & 15, kb = tid >> 4;
    const float* bsrc = nullptr;
    if (tid < 256)
        bsrc = dw_e + (size_t)(kb * 4) * HDIM + ht * 64 + nb * 4;

    f32x4 acc[2][4];
#pragma unroll
    for (int i = 0; i < 2; ++i)
#pragma unroll
        for (int f = 0; f < 4; ++f) acc[i][f] = (f32x4){0.f, 0.f, 0.f, 0.f};

    float4 br0, br1, br2, br3;
    if (tid < 256) {
        const float* sp = bsrc + (size_t)k0 * HDIM;
        br0 = *(const float4*)(sp);
        br1 = *(const float4*)(sp + HDIM);
        br2 = *(const float4*)(sp + 2 * HDIM);
        br3 = *(const float4*)(sp + 3 * HDIM);
    }

    for (int kk = k0; kk < kend; kk += 64) {
        __syncthreads();
        if (tid >= 256) {
#pragma unroll
            for (int i = 0; i < 8; ++i)
                gload16(asrc[i] + kk, As + ((size_t)(at + i * 256)) * 8);
        } else {
#pragma unroll
            for (int j = 0; j < 4; ++j) {
                int n = nb * 4 + j;
                int slot = kb ^ (n & 14);
                ushort4v b;
                b.x = f2b((&br0.x)[j]); b.y = f2b((&br1.x)[j]);
                b.z = f2b((&br2.x)[j]); b.w = f2b((&br3.x)[j]);
                *(ushort4v*)&Bs[n * 64 + slot * 4] = b;
            }
        }
        __syncthreads();
        if (tid < 256 && kk + 64 < kend) {
            const float* sp = bsrc + (size_t)(kk + 64) * HDIM;
            br0 = *(const float4*)(sp);
            br1 = *(const float4*)(sp + HDIM);
            br2 = *(const float4*)(sp + 2 * HDIM);
            br3 = *(const float4*)(sp + 3 * HDIM);
        }
        __builtin_amdgcn_s_setprio(1);
#pragma unroll
        for (int ks = 0; ks < 2; ++ks) {
            short8 a[2], b[4];
#pragma unroll
            for (int i = 0; i < 2; ++i) {
                int row = wave * 32 + i * 16 + l16;
                int q = ks * 4 + lq;
                a[i] = *(const short8*)&As[row * 64 + ((q ^ (row & 7)) * 8)];
            }
#pragma unroll
            for (int f = 0; f < 4; ++f) {
                int n = f * 16 + l16;
                int u = (ks * 8 + lq * 2) ^ (n & 14);
                b[f] = *(const short8*)&Bs[n * 64 + u * 4];
            }
#pragma unroll
            for (int i = 0; i < 2; ++i)
#pragma unroll
                for (int f = 0; f < 4; ++f)
                    acc[i][f] = __builtin_amdgcn_mfma_f32_16x16x32_bf16(a[i], b[f], acc[i][f], 0, 0, 0);
        }
        __builtin_amdgcn_s_setprio(0);
    }

    const float* db_e = db + (size_t)e * HDIM;
#pragma unroll
    for (int f = 0; f < 4; ++f) {
        int h = ht * 64 + f * 16 + l16;
        float bias = (ksp == 0) ? db_e[h] : 0.f;
#pragma unroll
        for (int i = 0; i < 2; ++i)
#pragma unroll
            for (int r = 0; r < 4; ++r) {
                int row = wave * 32 + i * 16 + lq * 4 + r;
                int tk = tokid[row];
                if (tk >= 0)
                    atomicAdd(out + (size_t)tk * HDIM + h, twt[row] * (acc[i][f][r] + bias));
            }
    }
}

// ---------------------------------------------------------------------------
extern "C" void kernel_launch(void* const* d_in, const int* in_sizes, int n_in,
                              void* d_out, int out_size, void* d_ws, size_t ws_size,
                              hipStream_t stream)
{
    const float* x   = (const float*)d_in[0];
    const float* gw  = (const float*)d_in[1];
    const float* gb  = (const float*)d_in[2];
    const float* gup = (const float*)d_in[3];
    const float* gub = (const float*)d_in[4];
    const float* dw  = (const float*)d_in[5];
    const float* db  = (const float*)d_in[6];

    float* out        = (float*)d_out;
    float* logits_out = out + (size_t)T_TOK * HDIM;

    char* ws = (char*)d_ws;
    int*   counts  = (int*)(ws + 0);
    int*   offsets = (int*)(ws + 256);
    int*   lists   = (int*)(ws + 512);                       // 64 KB
    float* wts     = (float*)(ws + 512 + 65536);             // 64 KB
    unsigned short* xb    = (unsigned short*)(ws + 131584);  // 2 MB
    unsigned short* inter = (unsigned short*)(ws + 2228736); // 23.6 MB

    hipMemsetAsync(counts, 0, 64, stream);

    router_kernel<<<T_TOK, 256, 0, stream>>>(x, gw, gb, logits_out, counts, lists, wts, xb, out);
    offsets_kernel<<<1, 64, 0, stream>>>(counts, offsets);
    gu_kernel<<<4 * NEXP * 90, 512, 0, stream>>>(xb, gup, gub, counts, offsets, lists, inter);
    down_kernel<<<4 * 2 * NEXP * 16, 512, 0, stream>>>(inter, dw, db, counts, offsets, lists, wts, out);
}

// Round 9
// 325.356 us; speedup vs baseline: 1.1330x; 1.0278x over previous
//
#include <hip/hip_runtime.h>
#include <hip/hip_bf16.h>
#include <stdint.h>

#define T_TOK 1024
#define HDIM  1024
#define NEXP  16
#define IDIM  2880
#define GU_COLS (2*IDIM)   // 5760
#define TOPK  4

using short4v  = __attribute__((ext_vector_type(4))) short;
using short8   = __attribute__((ext_vector_type(8))) short;
using ushort4v = __attribute__((ext_vector_type(4))) unsigned short;
using f32x4    = __attribute__((ext_vector_type(4))) float;

__device__ __forceinline__ unsigned short f2b(float f) {
    union { float f; unsigned u; } x; x.f = f;
    unsigned r = x.u + 0x7FFFu + ((x.u >> 16) & 1u);  // RNE
    return (unsigned short)(r >> 16);
}

typedef const __attribute__((address_space(1))) unsigned int* gas1_t;
typedef __attribute__((address_space(3))) unsigned int* las3_t;
__device__ __forceinline__ void gload16(const void* g, void* l) {
    __builtin_amdgcn_global_load_lds((gas1_t)g, (las3_t)l, 16, 0, 0);
}

// Raw-barrier pair (T4): role-split counted waits; loads survive barriers.
#define BAR_PRESTAGE() do { \
    asm volatile("s_waitcnt lgkmcnt(0)" ::: "memory"); \
    __builtin_amdgcn_s_barrier(); \
    __builtin_amdgcn_sched_barrier(0); \
} while (0)

#define BAR_PRECOMPUTE(is_a_wave) do { \
    if (is_a_wave) asm volatile("s_waitcnt vmcnt(0)" ::: "memory"); \
    else           asm volatile("s_waitcnt lgkmcnt(0)" ::: "memory"); \
    __builtin_amdgcn_s_barrier(); \
    __builtin_amdgcn_sched_barrier(0); \
} while (0)

// ---------------- Kernel 1: router + x->bf16 + zero out ---------------------
__global__ __launch_bounds__(256) void router_kernel(
    const float* __restrict__ x, const float* __restrict__ gw,
    const float* __restrict__ gb, float* __restrict__ logits_out,
    int* __restrict__ counts, int* __restrict__ lists, float* __restrict__ wts,
    unsigned short* __restrict__ xb, float* __restrict__ out)
{
    int t = blockIdx.x;
    int tid = threadIdx.x;
    const float* xr = x + (size_t)t * HDIM;
    {
        float4 v = *(const float4*)(xr + tid * 4);
        ushort4v b; b.x = f2b(v.x); b.y = f2b(v.y); b.z = f2b(v.z); b.w = f2b(v.w);
        *(ushort4v*)(xb + (size_t)t * HDIM + tid * 4) = b;
        float4 z = make_float4(0.f, 0.f, 0.f, 0.f);
        *(float4*)(out + (size_t)t * HDIM + tid * 4) = z;
    }
    int e = tid >> 4;
    int l16 = tid & 15;
    const float* wr = gw + (size_t)e * HDIM;
    float p = 0.f;
    for (int h = l16; h < HDIM; h += 16) p += xr[h] * wr[h];
    p += __shfl_xor(p, 8);
    p += __shfl_xor(p, 4);
    p += __shfl_xor(p, 2);
    p += __shfl_xor(p, 1);
    __shared__ float sl[NEXP];
    if (l16 == 0) {
        float v = p + gb[e];
        sl[e] = v;
        logits_out[t * NEXP + e] = v;
    }
    __syncthreads();
    if (tid == 0) {
        float v[NEXP];
#pragma unroll
        for (int i = 0; i < NEXP; ++i) v[i] = sl[i];
        int idx[TOPK]; float tv[TOPK];
        unsigned used = 0;
#pragma unroll
        for (int k = 0; k < TOPK; ++k) {
            float best = -__builtin_inff(); int bi = 0;
#pragma unroll
            for (int i = 0; i < NEXP; ++i)
                if (!((used >> i) & 1u) && v[i] > best) { best = v[i]; bi = i; }
            used |= 1u << bi; idx[k] = bi; tv[k] = best;
        }
        float m = tv[0];
        float ex[TOPK], s = 0.f;
#pragma unroll
        for (int k = 0; k < TOPK; ++k) { ex[k] = expf(tv[k] - m); s += ex[k]; }
#pragma unroll
        for (int k = 0; k < TOPK; ++k) {
            float w = ex[k] / s;
            int slot = atomicAdd(&counts[idx[k]], 1);
            lists[idx[k] * T_TOK + slot] = t;
            wts[idx[k] * T_TOK + slot] = w;
        }
    }
}

// ---------------- Kernel 2: exclusive prefix sum ---------------------------
__global__ void offsets_kernel(const int* __restrict__ counts, int* __restrict__ offsets)
{
    if (threadIdx.x == 0) {
        int o = 0;
        for (int e = 0; e < NEXP; ++e) { offsets[e] = o; o += counts[e]; }
        offsets[NEXP] = o;
    }
}

// ---------------- Kernel 3: gate_up GEMM + silu (direct fp32 weights) ------
// Round-5 geometry: BM=256, B tile 64 mixed rows (32 gate + 32 up cols),
// BK=64, 8 waves, wave = 32 rows x 64 B-rows, acc[2][4].
// NEW: raw-barrier counted-wait pipeline, B prefetch distance 2:
//   bc (bf16, ready) = tile k ; brf (fp32, in flight) = tile k+1;
//   phase k: write bc -> bar -> convert brf->bc, issue loads k+2 -> MFMA k.
__global__ __launch_bounds__(512) void gu_kernel(
    const unsigned short* __restrict__ xb, const float* __restrict__ gup,
    const float* __restrict__ gub, const int* __restrict__ counts,
    const int* __restrict__ offsets, const int* __restrict__ lists,
    unsigned short* __restrict__ inter)
{
    int bid = blockIdx.x;
    int nt = bid % 90;
    int t2 = bid / 90;
    int e  = t2 & 15;
    int mt = t2 >> 4;          // HIGH bits: 0..3
    int ne = counts[e];
    if (mt * 256 >= ne) return;

    int tid = threadIdx.x;
    int wave = tid >> 6, lane = tid & 63;
    int l16 = lane & 15, lq = lane >> 4;
    bool is_a_wave = (tid >= 256);

    __shared__ int tokid[256];
    __shared__ unsigned short As[256 * 64];   // 32 KB
    __shared__ unsigned short Bs[64 * 64];    // 8 KB

    if (tid < 256) {
        int slot = mt * 256 + tid;
        tokid[tid] = (slot < ne) ? lists[e * T_TOK + slot] : lists[e * T_TOK];
    }
    __syncthreads();

    const float* gup_e = gup + (size_t)e * HDIM * GU_COLS;

    // A stagers: threads 256..511, 8 x 16B chunks each
    int at = tid - 256;
    const unsigned short* asrc[8];
    if (is_a_wave) {
#pragma unroll
        for (int i = 0; i < 8; ++i) {
            int s = at + i * 256;
            int row = s >> 3, c = s & 7;
            asrc[i] = xb + (size_t)tokid[row] * HDIM + ((c ^ (row & 7)) * 8);
        }
    }
    // B stagers: threads 0..255: nb = n-block(4 cols), kb = k-chunk(4 rows)
    int nb = tid & 15, kb = tid >> 4;
    const float* bsrc = nullptr;
    if (!is_a_wave) {
        int n0 = nb * 4;
        size_t col = (n0 < 32) ? (size_t)(nt * 32 + n0) : (size_t)(IDIM + nt * 32 + (n0 - 32));
        bsrc = gup_e + (size_t)(kb * 4) * GU_COLS + col;
    }

    f32x4 acc[2][4];
#pragma unroll
    for (int i = 0; i < 2; ++i)
#pragma unroll
        for (int f = 0; f < 4; ++f) acc[i][f] = (f32x4){0.f, 0.f, 0.f, 0.f};

    // B pipeline regs
    float4  brf0, brf1, brf2, brf3;            // fp32 in flight (next+1 tile)
    ushort4v bc0, bc1, bc2, bc3;               // bf16 ready (next tile to write)

    // prologue: tile0 -> bc ; tile1 -> brf
    if (!is_a_wave) {
        brf0 = *(const float4*)(bsrc);
        brf1 = *(const float4*)(bsrc + GU_COLS);
        brf2 = *(const float4*)(bsrc + 2 * GU_COLS);
        brf3 = *(const float4*)(bsrc + 3 * GU_COLS);
        bc0 = (ushort4v){f2b(brf0.x), f2b(brf1.x), f2b(brf2.x), f2b(brf3.x)};
        bc1 = (ushort4v){f2b(brf0.y), f2b(brf1.y), f2b(brf2.y), f2b(brf3.y)};
        bc2 = (ushort4v){f2b(brf0.z), f2b(brf1.z), f2b(brf2.z), f2b(brf3.z)};
        bc3 = (ushort4v){f2b(brf0.w), f2b(brf1.w), f2b(brf2.w), f2b(brf3.w)};
        const float* sp = bsrc + (size_t)64 * GU_COLS;
        brf0 = *(const float4*)(sp);
        brf1 = *(const float4*)(sp + GU_COLS);
        brf2 = *(const float4*)(sp + 2 * GU_COLS);
        brf3 = *(const float4*)(sp + 3 * GU_COLS);
    }

    for (int kk = 0; kk < HDIM; kk += 64) {
        BAR_PRESTAGE();                         // prev readers done
        if (is_a_wave) {
#pragma unroll
            for (int i = 0; i < 8; ++i)
                gload16(asrc[i] + kk, As + ((size_t)(at + i * 256)) * 8);
        } else {
            // write tile kk from bc
            *(ushort4v*)&Bs[(nb * 4 + 0) * 64 + (kb ^ ((nb * 4 + 0) & 15)) * 4] = bc0;
            *(ushort4v*)&Bs[(nb * 4 + 1) * 64 + (kb ^ ((nb * 4 + 1) & 15)) * 4] = bc1;
            *(ushort4v*)&Bs[(nb * 4 + 2) * 64 + (kb ^ ((nb * 4 + 2) & 15)) * 4] = bc2;
            *(ushort4v*)&Bs[(nb * 4 + 3) * 64 + (kb ^ ((nb * 4 + 3) & 15)) * 4] = bc3;
        }
        BAR_PRECOMPUTE(is_a_wave);              // A DMA done / B writes visible
        if (!is_a_wave) {
            if (kk + 64 < HDIM) {               // convert tile kk+1 (auto-counted vmcnt)
                bc0 = (ushort4v){f2b(brf0.x), f2b(brf1.x), f2b(brf2.x), f2b(brf3.x)};
                bc1 = (ushort4v){f2b(brf0.y), f2b(brf1.y), f2b(brf2.y), f2b(brf3.y)};
                bc2 = (ushort4v){f2b(brf0.z), f2b(brf1.z), f2b(brf2.z), f2b(brf3.z)};
                bc3 = (ushort4v){f2b(brf0.w), f2b(brf1.w), f2b(brf2.w), f2b(brf3.w)};
            }
            if (kk + 128 < HDIM) {              // issue tile kk+2 loads
                const float* sp = bsrc + (size_t)(kk + 128) * GU_COLS;
                brf0 = *(const float4*)(sp);
                brf1 = *(const float4*)(sp + GU_COLS);
                brf2 = *(const float4*)(sp + 2 * GU_COLS);
                brf3 = *(const float4*)(sp + 3 * GU_COLS);
            }
        }
        __builtin_amdgcn_s_setprio(1);
#pragma unroll
        for (int ks = 0; ks < 2; ++ks) {
            short8 a[2], b[4];
#pragma unroll
            for (int i = 0; i < 2; ++i) {
                int row = wave * 32 + i * 16 + l16;
                int q = ks * 4 + lq;
                a[i] = *(const short8*)&As[row * 64 + ((q ^ (row & 7)) * 8)];
            }
#pragma unroll
            for (int f = 0; f < 4; ++f) {
                int n = f * 16 + l16;
                int u0 = (ks * 8 + lq * 2) ^ (n & 15);
                int u1 = (ks * 8 + lq * 2 + 1) ^ (n & 15);
                short4v h0 = *(const short4v*)&Bs[n * 64 + u0 * 4];
                short4v h1 = *(const short4v*)&Bs[n * 64 + u1 * 4];
                b[f] = __builtin_shufflevector(h0, h1, 0, 1, 2, 3, 4, 5, 6, 7);
            }
#pragma unroll
            for (int i = 0; i < 2; ++i)
#pragma unroll
                for (int f = 0; f < 4; ++f)
                    acc[i][f] = __builtin_amdgcn_mfma_f32_16x16x32_bf16(a[i], b[f], acc[i][f], 0, 0, 0);
        }
        __builtin_amdgcn_s_setprio(0);
    }

    // ---- epilogue: intra-wave silu(gate)*up ----
    int off = offsets[e];
    const float* gbe = gub + (size_t)e * GU_COLS;
#pragma unroll
    for (int j = 0; j < 2; ++j) {
        int col = j * 16 + l16;
        float bg = gbe[nt * 32 + col];
        float bu = gbe[IDIM + nt * 32 + col];
#pragma unroll
        for (int i = 0; i < 2; ++i)
#pragma unroll
            for (int r = 0; r < 4; ++r) {
                int row = wave * 32 + i * 16 + lq * 4 + r;
                int slot = mt * 256 + row;
                if (slot < ne) {
                    float g = acc[i][j][r] + bg;
                    float u = acc[i][j + 2][r] + bu;
                    float sg = g / (1.f + expf(-g));
                    inter[(size_t)(off + slot) * IDIM + nt * 32 + col] = f2b(sg * u);
                }
            }
    }
}

// ---------------- Kernel 4: down GEMM + weighted scatter (direct fp32) -----
// Round-5 geometry (no K-split): BM=256 x BN=64, K=IDIM (45 phases).
// Same raw-barrier distance-2 B pipeline as gu.
__global__ __launch_bounds__(512) void down_kernel(
    const unsigned short* __restrict__ inter, const float* __restrict__ dw,
    const float* __restrict__ db, const int* __restrict__ counts,
    const int* __restrict__ offsets, const int* __restrict__ lists,
    const float* __restrict__ wts, float* __restrict__ out)
{
    int bid = blockIdx.x;
    int ht  = bid & 15;
    int e   = (bid >> 4) & 15;
    int mt  = bid >> 8;        // HIGH bits: 0..3
    int ne = counts[e];
    if (mt * 256 >= ne) return;

    int tid = threadIdx.x;
    int wave = tid >> 6, lane = tid & 63;
    int l16 = lane & 15, lq = lane >> 4;
    bool is_a_wave = (tid >= 256);

    __shared__ int tokid[256];
    __shared__ float twt[256];
    __shared__ unsigned short As[256 * 64];   // 32 KB
    __shared__ unsigned short Bs[64 * 64];    // 8 KB

    int off = offsets[e];
    if (tid < 256) {
        int slot = mt * 256 + tid;
        tokid[tid] = (slot < ne) ? lists[e * T_TOK + slot] : -1;
        twt[tid]   = (slot < ne) ? wts[e * T_TOK + slot] : 0.f;
    }
    __syncthreads();

    const float* dw_e = dw + (size_t)e * IDIM * HDIM;

    int at = tid - 256;
    const unsigned short* asrc[8];
    if (is_a_wave) {
#pragma unroll
        for (int i = 0; i < 8; ++i) {
            int s = at + i * 256;
            int row = s >> 3, c = s & 7;
            int slotr = mt * 256 + row; if (slotr >= ne) slotr = ne - 1;
            asrc[i] = inter + (size_t)(off + slotr) * IDIM + ((c ^ (row & 7)) * 8);
        }
    }
    int nb = tid & 15, kb = tid >> 4;
    const float* bsrc = nullptr;
    if (!is_a_wave)
        bsrc = dw_e + (size_t)(kb * 4) * HDIM + ht * 64 + nb * 4;

    f32x4 acc[2][4];
#pragma unroll
    for (int i = 0; i < 2; ++i)
#pragma unroll
        for (int f = 0; f < 4; ++f) acc[i][f] = (f32x4){0.f, 0.f, 0.f, 0.f};

    float4  brf0, brf1, brf2, brf3;
    ushort4v bc0, bc1, bc2, bc3;

    if (!is_a_wave) {
        brf0 = *(const float4*)(bsrc);
        brf1 = *(const float4*)(bsrc + HDIM);
        brf2 = *(const float4*)(bsrc + 2 * HDIM);
        brf3 = *(const float4*)(bsrc + 3 * HDIM);
        bc0 = (ushort4v){f2b(brf0.x), f2b(brf1.x), f2b(brf2.x), f2b(brf3.x)};
        bc1 = (ushort4v){f2b(brf0.y), f2b(brf1.y), f2b(brf2.y), f2b(brf3.y)};
        bc2 = (ushort4v){f2b(brf0.z), f2b(brf1.z), f2b(brf2.z), f2b(brf3.z)};
        bc3 = (ushort4v){f2b(brf0.w), f2b(brf1.w), f2b(brf2.w), f2b(brf3.w)};
        const float* sp = bsrc + (size_t)64 * HDIM;
        brf0 = *(const float4*)(sp);
        brf1 = *(const float4*)(sp + HDIM);
        brf2 = *(const float4*)(sp + 2 * HDIM);
        brf3 = *(const float4*)(sp + 3 * HDIM);
    }

    for (int kk = 0; kk < IDIM; kk += 64) {
        BAR_PRESTAGE();
        if (is_a_wave) {
#pragma unroll
            for (int i = 0; i < 8; ++i)
                gload16(asrc[i] + kk, As + ((size_t)(at + i * 256)) * 8);
        } else {
            *(ushort4v*)&Bs[(nb * 4 + 0) * 64 + (kb ^ ((nb * 4 + 0) & 15)) * 4] = bc0;
            *(ushort4v*)&Bs[(nb * 4 + 1) * 64 + (kb ^ ((nb * 4 + 1) & 15)) * 4] = bc1;
            *(ushort4v*)&Bs[(nb * 4 + 2) * 64 + (kb ^ ((nb * 4 + 2) & 15)) * 4] = bc2;
            *(ushort4v*)&Bs[(nb * 4 + 3) * 64 + (kb ^ ((nb * 4 + 3) & 15)) * 4] = bc3;
        }
        BAR_PRECOMPUTE(is_a_wave);
        if (!is_a_wave) {
            if (kk + 64 < IDIM) {
                bc0 = (ushort4v){f2b(brf0.x), f2b(brf1.x), f2b(brf2.x), f2b(brf3.x)};
                bc1 = (ushort4v){f2b(brf0.y), f2b(brf1.y), f2b(brf2.y), f2b(brf3.y)};
                bc2 = (ushort4v){f2b(brf0.z), f2b(brf1.z), f2b(brf2.z), f2b(brf3.z)};
                bc3 = (ushort4v){f2b(brf0.w), f2b(brf1.w), f2b(brf2.w), f2b(brf3.w)};
            }
            if (kk + 128 < IDIM) {
                const float* sp = bsrc + (size_t)(kk + 128) * HDIM;
                brf0 = *(const float4*)(sp);
                brf1 = *(const float4*)(sp + HDIM);
                brf2 = *(const float4*)(sp + 2 * HDIM);
                brf3 = *(const float4*)(sp + 3 * HDIM);
            }
        }
        __builtin_amdgcn_s_setprio(1);
#pragma unroll
        for (int ks = 0; ks < 2; ++ks) {
            short8 a[2], b[4];
#pragma unroll
            for (int i = 0; i < 2; ++i) {
                int row = wave * 32 + i * 16 + l16;
                int q = ks * 4 + lq;
                a[i] = *(const short8*)&As[row * 64 + ((q ^ (row & 7)) * 8)];
            }
#pragma unroll
            for (int f = 0; f < 4; ++f) {
                int n = f * 16 + l16;
                int u0 = (ks * 8 + lq * 2) ^ (n & 15);
                int u1 = (ks * 8 + lq * 2 + 1) ^ (n & 15);
                short4v h0 = *(const short4v*)&Bs[n * 64 + u0 * 4];
                short4v h1 = *(const short4v*)&Bs[n * 64 + u1 * 4];
                b[f] = __builtin_shufflevector(h0, h1, 0, 1, 2, 3, 4, 5, 6, 7);
            }
#pragma unroll
            for (int i = 0; i < 2; ++i)
#pragma unroll
                for (int f = 0; f < 4; ++f)
                    acc[i][f] = __builtin_amdgcn_mfma_f32_16x16x32_bf16(a[i], b[f], acc[i][f], 0, 0, 0);
        }
        __builtin_amdgcn_s_setprio(0);
    }

    const float* db_e = db + (size_t)e * HDIM;
#pragma unroll
    for (int f = 0; f < 4; ++f) {
        int h = ht * 64 + f * 16 + l16;
        float bias = db_e[h];
#pragma unroll
        for (int i = 0; i < 2; ++i)
#pragma unroll
            for (int r = 0; r < 4; ++r) {
                int row = wave * 32 + i * 16 + lq * 4 + r;
                int tk = tokid[row];
                if (tk >= 0)
                    atomicAdd(out + (size_t)tk * HDIM + h, twt[row] * (acc[i][f][r] + bias));
            }
    }
}

// ---------------------------------------------------------------------------
extern "C" void kernel_launch(void* const* d_in, const int* in_sizes, int n_in,
                              void* d_out, int out_size, void* d_ws, size_t ws_size,
                              hipStream_t stream)
{
    const float* x   = (const float*)d_in[0];
    const float* gw  = (const float*)d_in[1];
    const float* gb  = (const float*)d_in[2];
    const float* gup = (const float*)d_in[3];
    const float* gub = (const float*)d_in[4];
    const float* dw  = (const float*)d_in[5];
    const float* db  = (const float*)d_in[6];

    float* out        = (float*)d_out;
    float* logits_out = out + (size_t)T_TOK * HDIM;

    char* ws = (char*)d_ws;
    int*   counts  = (int*)(ws + 0);
    int*   offsets = (int*)(ws + 256);
    int*   lists   = (int*)(ws + 512);                       // 64 KB
    float* wts     = (float*)(ws + 512 + 65536);             // 64 KB
    unsigned short* xb    = (unsigned short*)(ws + 131584);  // 2 MB
    unsigned short* inter = (unsigned short*)(ws + 2228736); // 23.6 MB

    hipMemsetAsync(counts, 0, 64, stream);

    router_kernel<<<T_TOK, 256, 0, stream>>>(x, gw, gb, logits_out, counts, lists, wts, xb, out);
    offsets_kernel<<<1, 64, 0, stream>>>(counts, offsets);
    gu_kernel<<<4 * NEXP * 90, 512, 0, stream>>>(xb, gup, gub, counts, offsets, lists, inter);
    down_kernel<<<4 * NEXP * 16, 512, 0, stream>>>(inter, dw, db, counts, offsets, lists, wts, out);
}